// Round 4
// baseline (92.106 us; speedup 1.0000x reference)
//
#include <hip/hip_runtime.h>
#include <hip/hip_bf16.h>

typedef float f32x4 __attribute__((ext_vector_type(4)));
typedef short bf16x8 __attribute__((ext_vector_type(8)));
typedef float float4v __attribute__((ext_vector_type(4)));

#define H1_STRIDE 40    // shorts; 32 + 8 pad
#define W1T_K 576
#define W2T_OFF (48 * 576)
#define PF 6            // fc1 A-load software-pipeline depth (48 VGPRs in flight)

__device__ __forceinline__ short f2bf(float f) {
  __bf16 b = (__bf16)f;
  return __builtin_bit_cast(short, b);
}
__device__ __forceinline__ uint pack2(float a, float b) {
  return (uint)(unsigned short)f2bf(a) | ((uint)(unsigned short)f2bf(b) << 16);
}
__device__ __forceinline__ float fast_sigmoid(float x) {
  return __builtin_amdgcn_rcpf(1.f + __expf(-x));
}
__device__ __forceinline__ float fast_tanh(float x) {
  float e = __expf(2.f * x);
  return 1.f - 2.f * __builtin_amdgcn_rcpf(e + 1.f);  // exact identity; saturates at +-1
}

// ---- prep: bf16 weight layouts in d_ws ----
// ws[0 .. 48*576)        : W1bT[n][k] = (n<32 ? W1[k][n] : n==32 ? Wr[k] : 0)   [K-contig]
// ws[48*576 .. +32*1024) : W2T[n][k] = W2[k][n]                                  [K-contig]
__global__ __launch_bounds__(256) void prep_weights(
    const float* __restrict__ W1, const float* __restrict__ W2,
    const float* __restrict__ Wr, short* __restrict__ ws)
{
  int i = blockIdx.x * 256 + threadIdx.x;
  if (i < 48 * 576) {
    int n = i / 576;
    int k = i - n * 576;
    float v = 0.f;
    if (n < 32) v = W1[k * 32 + n];
    else if (n == 32) v = Wr[k];
    ws[i] = f2bf(v);
  } else {
    int j = i - 48 * 576;
    if (j < 32 * 1024) {
      int n = j >> 5;
      int k = j & 31;
      ws[W2T_OFF + j] = f2bf(W2[k * 1024 + n]);
    }
  }
}

// All MFMAs computed TRANSPOSED (weights as A-operand, activations as B-operand).
// A/B frag maps are symmetric (lane&15, k=8*(lane>>4)+i), so the same loads feed
// the swapped form; D' layout gives each lane ONE batch row (m0+ln) and 4
// CONSECUTIVE output cols (4*lg+reg) -> dwordx4 prev_c loads & out stores.
__global__ __launch_bounds__(256, 4) void fclstm_main(
    const float* __restrict__ prev_h, const float* __restrict__ prev_c,
    const float* __restrict__ action, const float* __restrict__ dynamics,
    const float* __restrict__ b1, const float* __restrict__ b2,
    const float* __restrict__ Wr, const float* __restrict__ br,
    const short* __restrict__ wsw,
    float* __restrict__ out_h, float* __restrict__ out_c, float* __restrict__ out_r)
{
  __shared__ short h1T[64 * H1_STRIDE];  // 5,120 B : wave-local h1 transpose buffer

  const int t  = threadIdx.x;
  const int r0 = blockIdx.x * 64;

  const int wid  = t >> 6;
  const int lane = t & 63;
  const int lg   = lane >> 4;   // 16-lane group 0..3
  const int ln   = lane & 15;
  const int m0   = wid << 4;    // this wave's 16-row tile
  const int rowA = r0 + m0 + ln;   // THE batch row this lane owns (B-frag + epilogue)

  const int kb   = 8 * lg;
  const float* dynp = dynamics + rowA * 256 + kb;
  const float* actp = action   + rowA * 64  + kb;
  const float* hp   = prev_h   + rowA * 256 + kb;
  const short* w1f  = wsw + ln * W1T_K + kb;
  const float* pcp  = prev_c + (size_t)rowA * 256 + 4 * lg;

  auto asrc = [&](int j) -> const float* {
    return (j < 8) ? (dynp + 32 * j)
         : (j < 10) ? (actp + 32 * j - 256)
                    : (hp + 32 * j - 320);
  };

  // ---- fc1: h1pre' = W1bT x X^T, 6-deep explicit HBM pipeline on the A(X) loads
  f32x4 acc0 = {0.f,0.f,0.f,0.f};  // fc1 cols  0..15 (lane: col 4*lg+reg, row m0+ln)
  f32x4 acc1 = {0.f,0.f,0.f,0.f};  // fc1 cols 16..31
  f32x4 acc2 = {0.f,0.f,0.f,0.f};  // fc1 cols 32..47 (col 32 = x . Wr[0:576], lg==0,reg==0)

  float4v abuf[PF][2];
  #pragma unroll
  for (int j = 0; j < PF; ++j) {
    const float* p = asrc(j);
    abuf[j][0] = *(const float4v*)p;
    abuf[j][1] = *(const float4v*)(p + 4);
  }

  float4v pcA[8], pcB[8];

  #pragma unroll
  for (int j = 0; j < 18; ++j) {
    const int s = j % PF;
    bf16x8 a;
    {
      float4v v0 = abuf[s][0], v1 = abuf[s][1];
      a[0] = f2bf(v0.x); a[1] = f2bf(v0.y); a[2] = f2bf(v0.z); a[3] = f2bf(v0.w);
      a[4] = f2bf(v1.x); a[5] = f2bf(v1.y); a[6] = f2bf(v1.z); a[7] = f2bf(v1.w);
    }
    if (j + PF < 18) {
      const float* p = asrc(j + PF);
      abuf[s][0] = *(const float4v*)p;
      abuf[s][1] = *(const float4v*)(p + 4);
    }
    if (j == 8) {   // prev_c batch 0: ~10 fc1 iters + handoff of cover before use
      #pragma unroll
      for (int q = 0; q < 8; ++q) pcA[q] = *(const float4v*)(pcp + q * 16);
    }
    bf16x8 bA = *(const bf16x8*)(w1f + 32 * j);
    bf16x8 bB = *(const bf16x8*)(w1f + 16 * W1T_K + 32 * j);
    bf16x8 bC = *(const bf16x8*)(w1f + 32 * W1T_K + 32 * j);
    acc0 = __builtin_amdgcn_mfma_f32_16x16x32_bf16(bA, a, acc0, 0, 0, 0);
    acc1 = __builtin_amdgcn_mfma_f32_16x16x32_bf16(bB, a, acc1, 0, 0, 0);
    acc2 = __builtin_amdgcn_mfma_f32_16x16x32_bf16(bC, a, acc2, 0, 0, 0);
  }

  // prev_c batch 1 (tiles 8..15) — hides under handoff + first fc2 tiles
  #pragma unroll
  for (int q = 0; q < 8; ++q) pcB[q] = *(const float4v*)(pcp + 128 + q * 16);

  // ---- h1 = tanh(.+b1): lane holds row m0+ln, cols {4lg..4lg+3, 16+4lg..+3}.
  // Wave-local LDS transpose to build the fc2 B-frag (k=8*lg..+7 per lane).
  {
    float4v b1lo = *(const float4v*)&b1[4 * lg];
    float4v b1hi = *(const float4v*)&b1[16 + 4 * lg];
    uint2 wlo, whi;
    wlo.x = pack2(fast_tanh(acc0[0] + b1lo.x), fast_tanh(acc0[1] + b1lo.y));
    wlo.y = pack2(fast_tanh(acc0[2] + b1lo.z), fast_tanh(acc0[3] + b1lo.w));
    whi.x = pack2(fast_tanh(acc1[0] + b1hi.x), fast_tanh(acc1[1] + b1hi.y));
    whi.y = pack2(fast_tanh(acc1[2] + b1hi.z), fast_tanh(acc1[3] + b1hi.w));
    short* hrow = &h1T[(m0 + ln) * H1_STRIDE];
    *(uint2*)(hrow + 4 * lg)      = wlo;
    *(uint2*)(hrow + 16 + 4 * lg) = whi;
  }
  asm volatile("s_waitcnt lgkmcnt(0)" ::: "memory");
  __builtin_amdgcn_sched_barrier(0);
  bf16x8 af2 = *(const bf16x8*)(&h1T[(m0 + ln) * H1_STRIDE] + 8 * lg);

  // ---- fc2 + LSTM elementwise + reward ----
  float racc = 0.f;
  const float br0 = br[0];
  const short* w2t = wsw + W2T_OFF;
  const size_t orow = (size_t)rowA * 256;

  auto fc2_tile = [&](int nt, float4v pc) {
    const int c4 = nt * 16 + 4 * lg;                      // 4 consecutive out cols
    const short* aw = w2t + (nt * 16 + ln) * 32 + 8 * lg; // W2T rows as A-operand
    bf16x8 wi = *(const bf16x8*)(aw);
    bf16x8 wf = *(const bf16x8*)(aw + 256 * 32);
    bf16x8 wc = *(const bf16x8*)(aw + 512 * 32);
    bf16x8 wo = *(const bf16x8*)(aw + 768 * 32);
    f32x4 gi = {0.f,0.f,0.f,0.f}, gf = {0.f,0.f,0.f,0.f};
    f32x4 gc = {0.f,0.f,0.f,0.f}, go = {0.f,0.f,0.f,0.f};
    gi = __builtin_amdgcn_mfma_f32_16x16x32_bf16(wi, af2, gi, 0, 0, 0);
    gf = __builtin_amdgcn_mfma_f32_16x16x32_bf16(wf, af2, gf, 0, 0, 0);
    gc = __builtin_amdgcn_mfma_f32_16x16x32_bf16(wc, af2, gc, 0, 0, 0);
    go = __builtin_amdgcn_mfma_f32_16x16x32_bf16(wo, af2, go, 0, 0, 0);
    float4v b2i = *(const float4v*)&b2[c4];
    float4v b2f = *(const float4v*)&b2[256 + c4];
    float4v b2c = *(const float4v*)&b2[512 + c4];
    float4v b2o = *(const float4v*)&b2[768 + c4];
    float4v wrv = *(const float4v*)&Wr[576 + c4];
    float4v nh, nc2;
    #pragma unroll
    for (int r = 0; r < 4; ++r) {
      float iv  = fast_sigmoid(gi[r] + b2i[r]);
      float fv  = fast_sigmoid(gf[r] + b2f[r]);
      float cv  = fast_tanh(gc[r] + b2c[r]);
      float ov  = fast_sigmoid(go[r] + b2o[r]);
      float ncv = fv * pc[r] + iv * cv;
      float nhv = ov * fast_tanh(ncv);
      nh[r]  = nhv;
      nc2[r] = ncv;
      racc += nhv * wrv[r];
    }
    __builtin_nontemporal_store(nh,  (float4v*)(out_h + orow + c4));
    __builtin_nontemporal_store(nc2, (float4v*)(out_c + orow + c4));
  };

  #pragma unroll
  for (int q = 0; q < 8; ++q) fc2_tile(q, pcA[q]);
  #pragma unroll
  for (int q = 0; q < 8; ++q) fc2_tile(q + 8, pcB[q]);

  // reward: racc holds this lane's 64-col partial of row rowA; combine the 4 lg
  // groups, add x-part (acc2[0], valid on lg==0) + br, tanh.
  racc += __shfl_xor(racc, 16, 64);
  racc += __shfl_xor(racc, 32, 64);
  if (lg == 0) {
    float s = acc2[0] + racc + br0;
    __builtin_nontemporal_store(fast_tanh(s), &out_r[rowA]);
  }
}

extern "C" void kernel_launch(void* const* d_in, const int* in_sizes, int n_in,
                              void* d_out, int out_size, void* d_ws, size_t ws_size,
                              hipStream_t stream) {
  const float* prev_h   = (const float*)d_in[0];
  const float* prev_c   = (const float*)d_in[1];
  const float* action   = (const float*)d_in[2];
  const float* dynamics = (const float*)d_in[3];
  const float* W1 = (const float*)d_in[4];
  const float* b1 = (const float*)d_in[5];
  const float* W2 = (const float*)d_in[6];
  const float* b2 = (const float*)d_in[7];
  const float* Wr = (const float*)d_in[8];
  const float* br = (const float*)d_in[9];
  short* wsw = (short*)d_ws;   // needs 120,832 bytes

  float* out_h = (float*)d_out;
  float* out_c = out_h + (size_t)65536 * 256;
  float* out_r = out_c + (size_t)65536 * 256;

  prep_weights<<<236, 256, 0, stream>>>(W1, W2, Wr, wsw);
  fclstm_main<<<1024, 256, 0, stream>>>(prev_h, prev_c, action, dynamics,
                                        b1, b2, Wr, br, wsw, out_h, out_c, out_r);
}